// Round 4
// baseline (376.968 us; speedup 1.0000x reference)
//
#include <hip/hip_runtime.h>
#include <hip/hip_bf16.h>
#include <stdint.h>

// B=8, S=2048, D=512, H=2, hd=256. All dims hardcoded.
// Pipeline:
//   f2b converts -> proj GEMMs (bf16) -> gate -> QKV GEMM (writes Q compact
//   with 1/16*log2e scale folded, K/V in pre-chunked attention-ready layouts)
//   -> flash attention v4 (dual-chain interleaved QK(t)||PV(t-1), exp2 softmax)
//   -> gate-mix -> final GEMM (+residual, f32 out)

typedef __bf16 bf16_t;
typedef __bf16 bf16x8 __attribute__((ext_vector_type(8)));
typedef float f32x4 __attribute__((ext_vector_type(4)));
typedef float f32x16 __attribute__((ext_vector_type(16)));
typedef unsigned int u32;

typedef void gvoid_t __attribute__((address_space(1)));
typedef void svoid_t __attribute__((address_space(3)));

__device__ inline void gload16(const void* g, void* l) {
    __builtin_amdgcn_global_load_lds((gvoid_t*)g, (svoid_t*)l, 16, 0, 0);
}

__device__ inline u32 cvtpk_bf16(float lo, float hi) {
    u32 r;
    asm("v_cvt_pk_bf16_f32 %0, %1, %2" : "=v"(r) : "v"(lo), "v"(hi));
    return r;
}

__device__ inline float exp2v(float x) {
    float r;
    asm("v_exp_f32 %0, %1" : "=v"(r) : "v"(x));
    return r;
}

// ---------------- f32 -> bf16 convert ----------------
__global__ __launch_bounds__(256) void f2b_kernel(const float* __restrict__ in,
                                                  bf16_t* __restrict__ out, int n8) {
    int i = blockIdx.x * 256 + threadIdx.x;
    if (i >= n8) return;
    const float4* p = reinterpret_cast<const float4*>(in) + (size_t)i * 2;
    float4 a = p[0], b = p[1];
    bf16x8 o;
    o[0] = (bf16_t)a.x; o[1] = (bf16_t)a.y; o[2] = (bf16_t)a.z; o[3] = (bf16_t)a.w;
    o[4] = (bf16_t)b.x; o[5] = (bf16_t)b.y; o[6] = (bf16_t)b.z; o[7] = (bf16_t)b.w;
    reinterpret_cast<bf16x8*>(out)[i] = o;
}

// ---------------- GEMM: C = A @ B^T (+bias, + mode-specific epilogue) -------
// A: [M][K] bf16, B: [N][K] bf16. 128x128 tile, BK=64, 4 waves, 16x16x32 MFMA.
// MODE 0: store bf16 (acc+bias)
// MODE 1: QKV: Q (col<512) -> qdst[row][col] * (1/16)*log2(e)
//              K (512..1023) -> kdst chunked [bh][kt2][c=d/8][r=seq%32][e=d%8]
//              V (1024..)    -> vdst chunked [bh][kt2][kc=(seq%32)/8][d][e=seq%8]
// MODE 2: store f32  acc+bias + 0.5*(r1+r2)                 (final out-proj)
template <int MODE>
__global__ __launch_bounds__(256) void gemm_bt(const bf16_t* __restrict__ A,
                                               const bf16_t* __restrict__ Bw,
                                               const float* __restrict__ bias,
                                               void* __restrict__ Cout,
                                               const bf16_t* __restrict__ r1,
                                               const bf16_t* __restrict__ r2,
                                               bf16_t* __restrict__ qdst,
                                               bf16_t* __restrict__ kdst,
                                               bf16_t* __restrict__ vdst,
                                               int M, int N, int K) {
    __shared__ __align__(16) bf16_t As[128][64];
    __shared__ __align__(16) bf16_t Bs[128][64];
    const int tid = threadIdx.x, lane = tid & 63, w = tid >> 6;
    const int l16 = lane & 15, l4 = lane >> 4;
    const int wm = w >> 1, wn = w & 1;
    const size_t a0 = (size_t)blockIdx.y * 128;
    const size_t b0 = (size_t)blockIdx.x * 128;
    f32x4 acc[4][4] = {};
    const int srow = w * 32 + (lane >> 3);
    const int scol = (lane & 7) * 8;
    for (int kt = 0; kt < K; kt += 64) {
        __syncthreads();
#pragma unroll
        for (int i = 0; i < 4; ++i) {
            gload16(A + (a0 + srow + i * 8) * (size_t)K + kt + scol, &As[w * 32 + i * 8][0]);
            gload16(Bw + (b0 + srow + i * 8) * (size_t)K + kt + scol, &Bs[w * 32 + i * 8][0]);
        }
        __syncthreads();
#pragma unroll
        for (int kk = 0; kk < 2; ++kk) {
            bf16x8 af[4], bfr[4];
#pragma unroll
            for (int mi = 0; mi < 4; ++mi)
                af[mi] = *reinterpret_cast<const bf16x8*>(&As[wm * 64 + mi * 16 + l16][kk * 32 + l4 * 8]);
#pragma unroll
            for (int ni = 0; ni < 4; ++ni)
                bfr[ni] = *reinterpret_cast<const bf16x8*>(&Bs[wn * 64 + ni * 16 + l16][kk * 32 + l4 * 8]);
#pragma unroll
            for (int mi = 0; mi < 4; ++mi)
#pragma unroll
                for (int ni = 0; ni < 4; ++ni)
                    acc[mi][ni] = __builtin_amdgcn_mfma_f32_16x16x32_bf16(af[mi], bfr[ni], acc[mi][ni], 0, 0, 0);
        }
    }
#pragma unroll
    for (int mi = 0; mi < 4; ++mi) {
#pragma unroll
        for (int ni = 0; ni < 4; ++ni) {
            int col = (int)b0 + wn * 64 + ni * 16 + l16;
            float bs = bias[col];
            int row0 = (int)a0 + wm * 64 + mi * 16 + l4 * 4;
            float vv[4];
#pragma unroll
            for (int r = 0; r < 4; ++r) vv[r] = acc[mi][ni][r] + bs;
            if (MODE == 0) {
#pragma unroll
                for (int r = 0; r < 4; ++r)
                    ((bf16_t*)Cout)[(size_t)(row0 + r) * N + col] = (bf16_t)vv[r];
            } else if (MODE == 2) {
#pragma unroll
                for (int r = 0; r < 4; ++r) {
                    size_t idx = (size_t)(row0 + r) * N + col;
                    ((float*)Cout)[idx] = vv[r] + 0.5f * ((float)r1[idx] + (float)r2[idx]);
                }
            } else {
                if (col < 512) {
#pragma unroll
                    for (int r = 0; r < 4; ++r)
                        qdst[(size_t)(row0 + r) * 512 + col] = (bf16_t)(vv[r] * 0.090168440f);
                } else if (col < 1024) {
                    int cc = col - 512, h = cc >> 8, d = cc & 255;
#pragma unroll
                    for (int r = 0; r < 4; ++r) {
                        int row = row0 + r;
                        int bh = (row >> 11) * 2 + h, seq = row & 2047;
                        kdst[((size_t)(bh * 64 + (seq >> 5))) * 8192 + (d >> 3) * 256 +
                             (seq & 31) * 8 + (d & 7)] = (bf16_t)vv[r];
                    }
                } else {
                    int cc = col - 1024, h = cc >> 8, d = cc & 255;
                    int bh = (row0 >> 11) * 2 + h, seq = row0 & 2047;
                    size_t idx = ((size_t)(bh * 64 + (seq >> 5))) * 8192 +
                                 ((seq >> 3) & 3) * 2048 + d * 8 + (seq & 7);
                    union { bf16_t h4[4]; uint2 u8; } pk;
#pragma unroll
                    for (int r = 0; r < 4; ++r) pk.h4[r] = (bf16_t)vv[r];
                    *reinterpret_cast<uint2*>(&vdst[idx]) = pk.u8;
                }
            }
        }
    }
}

// ---------------- gate = sigmoid(sum(rgb_p*event_p, axis=-1)) ----------------
__global__ __launch_bounds__(256) void gate_kernel(const bf16_t* __restrict__ rp,
                                                   const bf16_t* __restrict__ ep,
                                                   float* __restrict__ gate) {
    int row = blockIdx.x * 4 + (threadIdx.x >> 6);
    int lane = threadIdx.x & 63;
    bf16x8 a = reinterpret_cast<const bf16x8*>(rp + (size_t)row * 512)[lane];
    bf16x8 b = reinterpret_cast<const bf16x8*>(ep + (size_t)row * 512)[lane];
    float s = 0.f;
#pragma unroll
    for (int j = 0; j < 8; ++j) s += (float)a[j] * (float)b[j];
#pragma unroll
    for (int off = 32; off; off >>= 1) s += __shfl_xor(s, off, 64);
    if (lane == 0) gate[row] = 1.f / (1.f + __expf(-s));
}

// ---------------- flash attention v4 ----------------
// grid 512: bid = qb*32 + dir*16 + bh. 4 waves, wave owns 32 q rows, KVBLK=32.
// Dual-chain pipeline: body t = {stage K(t+1),V(t); softmax(st[t-1]);
// QK(t) MFMAs interleaved 1:1 with PV(t-1) MFMAs}. K/V double-buffered,
// V staged one iter behind K. exp2-domain softmax (log2e folded into Q).
__global__ __launch_bounds__(256, 2) void attn_kernel(const bf16_t* __restrict__ qbr,
                                                      const bf16_t* __restrict__ qbe,
                                                      const bf16_t* __restrict__ kbr,
                                                      const bf16_t* __restrict__ kbe,
                                                      const bf16_t* __restrict__ vbr,
                                                      const bf16_t* __restrict__ vbe,
                                                      bf16_t* __restrict__ out0,
                                                      bf16_t* __restrict__ out1) {
    __shared__ __align__(16) bf16_t smem[32768];  // K[2][8192] | V[2][8192]
    const int bid = blockIdx.x;
    const int qb = bid >> 5;
    const int combo = bid & 31;
    const int dir = combo >> 4;
    const int bh = combo & 15;
    const int b = bh >> 1, h = bh & 1;
    const bf16_t* Qb = dir ? qbe : qbr;
    const bf16_t* Kc = dir ? kbr : kbe;
    const bf16_t* Vc = dir ? vbr : vbe;
    bf16_t* osrc = dir ? out1 : out0;
    const int tid = threadIdx.x;
    const int w = tid >> 6, l = tid & 63;
    const int l31 = l & 31, hi = l >> 5;
    const int q0w = qb * 128 + w * 32;

    // Q fragments (B-operand): lane holds Q[q0w + l31][dch*16 + hi*8 + j]
    const bf16_t* qp = Qb + ((size_t)(b * 2048 + q0w + l31)) * 512 + h * 256 + hi * 8;
    bf16x8 qf[16];
#pragma unroll
    for (int dch = 0; dch < 16; ++dch)
        qf[dch] = *reinterpret_cast<const bf16x8*>(qp + dch * 16);

    f32x16 O[8] = {};
    f32x16 stA, stB;
    float mrun = -1e30f, lrun = 0.f;
    union PA { u32 uw[4]; bf16x8 v; } pa0, pa1;

    const bf16_t* kq = Kc + (size_t)bh * 524288 + (w * 2048 + l * 8);
    const bf16_t* vq = Vc + (size_t)bh * 524288 + (w * 2048 + l * 8);

#define SK_(T, P)                                                      \
    do {                                                               \
        const bf16_t* s_ = kq + (size_t)(T) * 8192;                    \
        bf16_t* d_ = &smem[(P) * 8192 + w * 2048];                     \
        gload16(s_, d_); gload16(s_ + 512, d_ + 512);                  \
        gload16(s_ + 1024, d_ + 1024); gload16(s_ + 1536, d_ + 1536);  \
    } while (0)
#define SV_(T, P)                                                      \
    do {                                                               \
        const bf16_t* s_ = vq + (size_t)(T) * 8192;                    \
        bf16_t* d_ = &smem[16384 + (P) * 8192 + w * 2048];             \
        gload16(s_, d_); gload16(s_ + 512, d_ + 512);                  \
        gload16(s_ + 1024, d_ + 1024); gload16(s_ + 1536, d_ + 1536);  \
    } while (0)

#define SOFTMAX(STP)                                                          \
    do {                                                                      \
        float mx_ = STP[0];                                                   \
        _Pragma("unroll") for (int r_ = 1; r_ < 16; ++r_)                     \
            mx_ = fmaxf(mx_, STP[r_]);                                        \
        mx_ = fmaxf(mx_, __shfl_xor(mx_, 32, 64));                            \
        if (__any(mx_ - mrun > 8.f)) {                                        \
            float mnew_ = fmaxf(mrun, mx_);                                   \
            float sc_ = exp2v(mrun - mnew_);                                  \
            mrun = mnew_; lrun *= sc_;                                        \
            _Pragma("unroll") for (int r_ = 0; r_ < 16; ++r_) {               \
                int qr_ = (r_ & 3) + 8 * (r_ >> 2) + 4 * hi;                  \
                float scr_ = __shfl(sc_, qr_, 64);                            \
                _Pragma("unroll") for (int g_ = 0; g_ < 8; ++g_)              \
                    O[g_][r_] *= scr_;                                        \
            }                                                                 \
        }                                                                     \
        float ls_ = 0.f;                                                      \
        u32 W_[8];                                                            \
        _Pragma("unroll") for (int m_ = 0; m_ < 8; ++m_) {                    \
            float plo_ = exp2v(STP[2 * m_] - mrun);                           \
            float phi_ = exp2v(STP[2 * m_ + 1] - mrun);                       \
            ls_ += plo_ + phi_;                                               \
            W_[m_] = cvtpk_bf16(plo_, phi_);                                  \
        }                                                                     \
        ls_ += __shfl_xor(ls_, 32, 64);                                       \
        lrun += ls_;                                                          \
        {                                                                     \
            u32 t0_ = hi ? W_[0] : W_[2], t1_ = hi ? W_[1] : W_[3];           \
            u32 r0_ = (u32)__shfl_xor((int)t0_, 32, 64);                      \
            u32 r1_ = (u32)__shfl_xor((int)t1_, 32, 64);                      \
            pa0.uw[0] = hi ? r0_ : W_[0]; pa0.uw[1] = hi ? r1_ : W_[1];       \
            pa0.uw[2] = hi ? W_[2] : r0_; pa0.uw[3] = hi ? W_[3] : r1_;       \
        }                                                                     \
        {                                                                     \
            u32 t0_ = hi ? W_[4] : W_[6], t1_ = hi ? W_[5] : W_[7];           \
            u32 r0_ = (u32)__shfl_xor((int)t0_, 32, 64);                      \
            u32 r1_ = (u32)__shfl_xor((int)t1_, 32, 64);                      \
            pa1.uw[0] = hi ? r0_ : W_[4]; pa1.uw[1] = hi ? r1_ : W_[5];       \
            pa1.uw[2] = hi ? W_[6] : r0_; pa1.uw[3] = hi ? W_[7] : r1_;       \
        }                                                                     \
    } while (0)

#define QK_ONLY(STN, KPR)                                                     \
    do {                                                                      \
        const bf16_t* kb_ = &smem[(KPR) * 8192 + hi * 256 + l31 * 8];         \
        _Pragma("unroll") for (int r_ = 0; r_ < 16; ++r_) STN[r_] = 0.f;      \
        _Pragma("unroll") for (int d_ = 0; d_ < 16; ++d_) {                   \
            bf16x8 kf_ = *reinterpret_cast<const bf16x8*>(kb_ + d_ * 512);    \
            STN = __builtin_amdgcn_mfma_f32_32x32x16_bf16(kf_, qf[d_], STN, 0, 0, 0); \
        }                                                                     \
    } while (0)

#define QKPV(STN, KPR, VPR)                                                   \
    do {                                                                      \
        const bf16_t* kb_ = &smem[(KPR) * 8192 + hi * 256 + l31 * 8];         \
        const bf16_t* vb_ = &smem[16384 + (VPR) * 8192 + hi * 2048 + l31 * 8];\
        _Pragma("unroll") for (int r_ = 0; r_ < 16; ++r_) STN[r_] = 0.f;      \
        __builtin_amdgcn_s_setprio(1);                                        \
        _Pragma("unroll") for (int i_ = 0; i_ < 8; ++i_) {                    \
            bf16x8 k0_ = *reinterpret_cast<const bf16x8*>(kb_ + (2 * i_) * 512); \
            STN = __builtin_amdgcn_mfma_f32_32x32x16_bf16(k0_, qf[2 * i_], STN, 0, 0, 0); \
            bf16x8 v0_ = *reinterpret_cast<const bf16x8*>(vb_ + i_ * 256);    \
            O[i_] = __builtin_amdgcn_mfma_f32_32x32x16_bf16(pa0.v, v0_, O[i_], 0, 0, 0); \
            bf16x8 k1_ = *reinterpret_cast<const bf16x8*>(kb_ + (2 * i_ + 1) * 512); \
            STN = __builtin_amdgcn_mfma_f32_32x32x16_bf16(k1_, qf[2 * i_ + 1], STN, 0, 0, 0); \
            if (i_ > 0) {                                                     \
                bf16x8 v1_ = *reinterpret_cast<const bf16x8*>(vb_ + 4096 + (i_ - 1) * 256); \
                O[i_ - 1] = __builtin_amdgcn_mfma_f32_32x32x16_bf16(pa1.v, v1_, O[i_ - 1], 0, 0, 0); \
            }                                                                 \
        }                                                                     \
        {                                                                     \
            bf16x8 v1_ = *reinterpret_cast<const bf16x8*>(vb_ + 4096 + 7 * 256); \
            O[7] = __builtin_amdgcn_mfma_f32_32x32x16_bf16(pa1.v, v1_, O[7], 0, 0, 0); \
        }                                                                     \
        __builtin_amdgcn_s_setprio(0);                                        \
    } while (0)

#define PV_ONLY(VPR)                                                          \
    do {                                                                      \
        const bf16_t* vb_ = &smem[16384 + (VPR) * 8192 + hi * 2048 + l31 * 8];\
        _Pragma("unroll") for (int g_ = 0; g_ < 8; ++g_) {                    \
            bf16x8 v0_ = *reinterpret_cast<const bf16x8*>(vb_ + g_ * 256);    \
            O[g_] = __builtin_amdgcn_mfma_f32_32x32x16_bf16(pa0.v, v0_, O[g_], 0, 0, 0); \
        }                                                                     \
        _Pragma("unroll") for (int g_ = 0; g_ < 8; ++g_) {                    \
            bf16x8 v1_ = *reinterpret_cast<const bf16x8*>(vb_ + 4096 + g_ * 256); \
            O[g_] = __builtin_amdgcn_mfma_f32_32x32x16_bf16(pa1.v, v1_, O[g_], 0, 0, 0); \
        }                                                                     \
    } while (0)

#define SYNC()                                              \
    asm volatile("s_waitcnt vmcnt(0)" ::: "memory");        \
    __builtin_amdgcn_s_barrier();

    // prologue: stage K(0)
    SK_(0, 0);
    // body 0: stage K(1)|slot1, V(0)|slot0; QK(0)->stA
    SYNC();
    SK_(1, 1);
    SV_(0, 0);
    QK_ONLY(stA, 0);
    // bodies 1..62 (31 ping-pong pairs)
    for (int tb = 0; tb < 31; ++tb) {
        const int t1 = 2 * tb + 1, t2 = 2 * tb + 2;
        SYNC();
        SK_(t1 + 1, 0);
        SV_(t1, 1);
        SOFTMAX(stA);
        QKPV(stB, 1, 0);
        SYNC();
        SK_(t2 + 1, 1);
        SV_(t2, 0);
        SOFTMAX(stB);
        QKPV(stA, 0, 1);
    }
    // body 63: stage V(63)|slot1 only
    SYNC();
    SV_(63, 1);
    SOFTMAX(stA);
    QKPV(stB, 1, 0);
    // epilogue body: softmax(st[63]) + PV(63)
    SYNC();
    SOFTMAX(stB);
    PV_ONLY(1);

#undef SK_
#undef SV_
#undef SOFTMAX
#undef QK_ONLY
#undef QKPV
#undef PV_ONLY
#undef SYNC

    // normalize (lrun broadcast per q-row) and store
#pragma unroll
    for (int r = 0; r < 16; ++r) {
        int qr = (r & 3) + 8 * (r >> 2) + 4 * hi;
        float linv = 1.0f / __shfl(lrun, qr, 64);
        size_t rowoff = ((size_t)(b * 2048 + q0w + qr)) * 512 + h * 256 + l31;
#pragma unroll
        for (int g = 0; g < 8; ++g)
            osrc[rowoff + g * 32] = (bf16_t)(O[g][r] * linv);
    }
}

// ---------------- mix: gate*attn1 + (1-gate)*attn2 -> bf16 ----------------
__global__ __launch_bounds__(256) void mix_kernel(const bf16_t* __restrict__ a1,
                                                  const bf16_t* __restrict__ a2,
                                                  const float* __restrict__ gate,
                                                  bf16_t* __restrict__ outm) {
    int i = blockIdx.x * 256 + threadIdx.x;
    int m = i >> 6;
    float g = gate[m];
    bf16x8 x = reinterpret_cast<const bf16x8*>(a1)[i];
    bf16x8 y = reinterpret_cast<const bf16x8*>(a2)[i];
    bf16x8 o;
#pragma unroll
    for (int j = 0; j < 8; ++j) o[j] = (bf16_t)(g * (float)x[j] + (1.f - g) * (float)y[j]);
    reinterpret_cast<bf16x8*>(outm)[i] = o;
}

extern "C" void kernel_launch(void* const* d_in, const int* in_sizes, int n_in,
                              void* d_out, int out_size, void* d_ws, size_t ws_size,
                              hipStream_t stream) {
    const float* rgb = (const float*)d_in[0];
    const float* event = (const float*)d_in[1];
    const float* w_rgb = (const float*)d_in[2];
    const float* b_rgb = (const float*)d_in[3];
    const float* w_event = (const float*)d_in[4];
    const float* b_event = (const float*)d_in[5];
    const float* w_in = (const float*)d_in[6];
    const float* b_in = (const float*)d_in[7];
    const float* w_out = (const float*)d_in[8];
    const float* b_out = (const float*)d_in[9];
    float* out = (float*)d_out;

    const int M = 16384;  // B*S
    const size_t MB16 = (size_t)16 * 1024 * 1024;
    char* ws = (char*)d_ws;
    bf16_t* wrgb_bf = (bf16_t*)(ws + 0);
    bf16_t* wevt_bf = (bf16_t*)(ws + 524288);
    bf16_t* wout_bf = (bf16_t*)(ws + 1048576);
    bf16_t* win_bf = (bf16_t*)(ws + 1572864);
    float* gate = (float*)(ws + 3145728);
    bf16_t* bufA = (bf16_t*)(ws + 4194304);            // rgb bf16 -> attn out dir0
    bf16_t* bufB = (bf16_t*)(ws + 4194304 + MB16);     // event bf16 -> attn out dir1
    bf16_t* rgbp = (bf16_t*)(ws + 4194304 + 2 * MB16);
    bf16_t* evtp = (bf16_t*)(ws + 4194304 + 3 * MB16);
    bf16_t* qbr  = (bf16_t*)(ws + 4194304 + 4 * MB16);
    bf16_t* qbe  = (bf16_t*)(ws + 4194304 + 5 * MB16);
    bf16_t* kbr  = (bf16_t*)(ws + 4194304 + 6 * MB16);
    bf16_t* kbe  = (bf16_t*)(ws + 4194304 + 7 * MB16);
    bf16_t* vbr  = (bf16_t*)(ws + 4194304 + 8 * MB16);
    bf16_t* vbe  = (bf16_t*)(ws + 4194304 + 9 * MB16);
    bf16_t* mixed = (bf16_t*)(ws + 4194304 + 10 * MB16);

    dim3 blk(256);
    // converts
    f2b_kernel<<<4096, blk, 0, stream>>>(rgb, bufA, M * 512 / 8);
    f2b_kernel<<<4096, blk, 0, stream>>>(event, bufB, M * 512 / 8);
    f2b_kernel<<<128, blk, 0, stream>>>(w_rgb, wrgb_bf, 512 * 512 / 8);
    f2b_kernel<<<128, blk, 0, stream>>>(w_event, wevt_bf, 512 * 512 / 8);
    f2b_kernel<<<384, blk, 0, stream>>>(w_in, win_bf, 1536 * 512 / 8);
    f2b_kernel<<<128, blk, 0, stream>>>(w_out, wout_bf, 512 * 512 / 8);
    // input projections
    gemm_bt<0><<<dim3(4, 128), blk, 0, stream>>>(bufA, wrgb_bf, b_rgb, rgbp, nullptr, nullptr,
                                                 nullptr, nullptr, nullptr, M, 512, 512);
    gemm_bt<0><<<dim3(4, 128), blk, 0, stream>>>(bufB, wevt_bf, b_event, evtp, nullptr, nullptr,
                                                 nullptr, nullptr, nullptr, M, 512, 512);
    // gate
    gate_kernel<<<4096, blk, 0, stream>>>(rgbp, evtp, gate);
    // QKV projections -> Q compact + K/V chunked layouts (scales folded in)
    gemm_bt<1><<<dim3(12, 128), blk, 0, stream>>>(rgbp, win_bf, b_in, nullptr, nullptr, nullptr,
                                                  qbr, kbr, vbr, M, 1536, 512);
    gemm_bt<1><<<dim3(12, 128), blk, 0, stream>>>(evtp, win_bf, b_in, nullptr, nullptr, nullptr,
                                                  qbe, kbe, vbe, M, 1536, 512);
    // attention both directions
    attn_kernel<<<512, blk, 0, stream>>>(qbr, qbe, kbr, kbe, vbr, vbe, bufA, bufB);
    // gated mix
    mix_kernel<<<4096, blk, 0, stream>>>(bufA, bufB, gate, mixed);
    // final projection + residual, f32 out
    gemm_bt<2><<<dim3(4, 128), blk, 0, stream>>>(mixed, wout_bf, b_out, out, rgbp, evtp,
                                                 nullptr, nullptr, nullptr, M, 512, 512);
}

// Round 5
// 355.831 us; speedup vs baseline: 1.0594x; 1.0594x over previous
//
#include <hip/hip_runtime.h>
#include <hip/hip_bf16.h>
#include <stdint.h>

// B=8, S=2048, D=512, H=2, hd=256. All dims hardcoded.
// 6 dispatches: f2b_all -> proj GEMM (merged rgb+event) -> gate
//   -> QKV GEMM (merged, Q*1/16*log2e, K/V pre-chunked) -> attn (phase-serial,
//   exp2 softmax, setprio) -> final GEMM (mix fused in A-staging, +residual, f32)

typedef __bf16 bf16_t;
typedef __bf16 bf16x8 __attribute__((ext_vector_type(8)));
typedef float f32x4 __attribute__((ext_vector_type(4)));
typedef float f32x16 __attribute__((ext_vector_type(16)));
typedef unsigned int u32;

typedef void gvoid_t __attribute__((address_space(1)));
typedef void svoid_t __attribute__((address_space(3)));

__device__ inline void gload16(const void* g, void* l) {
    __builtin_amdgcn_global_load_lds((gvoid_t*)g, (svoid_t*)l, 16, 0, 0);
}

__device__ inline u32 cvtpk_bf16(float lo, float hi) {
    u32 r;
    asm("v_cvt_pk_bf16_f32 %0, %1, %2" : "=v"(r) : "v"(lo), "v"(hi));
    return r;
}

__device__ inline float exp2v(float x) {
    float r;
    asm("v_exp_f32 %0, %1" : "=v"(r) : "v"(x));
    return r;
}

// ---------------- all f32 -> bf16 converts in one dispatch ----------------
// segments (vec8 units): rgb 1048576 | event 1048576 | w_rgb 32768 |
// w_event 32768 | w_in 98304 | w_out 32768 ; total 2293760 -> grid 8960
__global__ __launch_bounds__(256) void f2b_all(const float* __restrict__ s0, bf16_t* __restrict__ d0,
                                               const float* __restrict__ s1, bf16_t* __restrict__ d1,
                                               const float* __restrict__ s2, bf16_t* __restrict__ d2,
                                               const float* __restrict__ s3, bf16_t* __restrict__ d3,
                                               const float* __restrict__ s4, bf16_t* __restrict__ d4,
                                               const float* __restrict__ s5, bf16_t* __restrict__ d5) {
    int i = blockIdx.x * 256 + threadIdx.x;
    const float* s; bf16_t* d; int off;
    if (i < 1048576)      { s = s0; d = d0; off = i; }
    else if (i < 2097152) { s = s1; d = d1; off = i - 1048576; }
    else if (i < 2129920) { s = s2; d = d2; off = i - 2097152; }
    else if (i < 2162688) { s = s3; d = d3; off = i - 2129920; }
    else if (i < 2260992) { s = s4; d = d4; off = i - 2162688; }
    else                  { s = s5; d = d5; off = i - 2260992; }
    const float4* p = reinterpret_cast<const float4*>(s) + (size_t)off * 2;
    float4 a = p[0], b = p[1];
    bf16x8 o;
    o[0] = (bf16_t)a.x; o[1] = (bf16_t)a.y; o[2] = (bf16_t)a.z; o[3] = (bf16_t)a.w;
    o[4] = (bf16_t)b.x; o[5] = (bf16_t)b.y; o[6] = (bf16_t)b.z; o[7] = (bf16_t)b.w;
    reinterpret_cast<bf16x8*>(d)[off] = o;
}

// ---------------- GEMM: C = A @ B^T, 128x128 tile, BK=64, 4 waves ----------
// MODE 0 (proj, merged): blockIdx.y<128 -> (A,Bw,bias,C); else (A2,Bw2,bias2,C2)
// MODE 1 (QKV, merged): Q -> qdst[row][col]*(1/16*log2e); K/V -> chunked layouts
// MODE 2 (final): A-staging = gate-mix of A(bufA),A2(bufB); f32 out + residual
template <int MODE>
__global__ __launch_bounds__(256) void gemm_bt(const bf16_t* __restrict__ A,
                                               const bf16_t* __restrict__ A2,
                                               const bf16_t* __restrict__ Bw,
                                               const bf16_t* __restrict__ Bw2,
                                               const float* __restrict__ bias,
                                               const float* __restrict__ bias2,
                                               void* __restrict__ Cout,
                                               void* __restrict__ Cout2,
                                               const bf16_t* __restrict__ r1,
                                               const bf16_t* __restrict__ r2,
                                               const float* __restrict__ gate,
                                               bf16_t* __restrict__ qdst,
                                               bf16_t* __restrict__ kdst,
                                               bf16_t* __restrict__ vdst,
                                               bf16_t* __restrict__ qdst2,
                                               bf16_t* __restrict__ kdst2,
                                               bf16_t* __restrict__ vdst2,
                                               int N, int K) {
    __shared__ __align__(16) bf16_t As[128][64];
    __shared__ __align__(16) bf16_t Bs[128][64];
    const int tid = threadIdx.x, lane = tid & 63, w = tid >> 6;
    const int l16 = lane & 15, l4 = lane >> 4;
    const int wm = w >> 1, wn = w & 1;
    const bool sec = (MODE != 2) && (blockIdx.y >= 128);
    const size_t a0 = (size_t)(blockIdx.y & 127) * 128;
    const size_t b0 = (size_t)blockIdx.x * 128;
    const bf16_t* Ap = sec ? A2 : A;
    const bf16_t* Bp = sec ? Bw2 : Bw;
    const float* bp = sec ? bias2 : bias;
    f32x4 acc[4][4] = {};
    const int srow = w * 32 + (lane >> 3);
    const int scol = (lane & 7) * 8;
    float g4[4];
    if (MODE == 2) {
#pragma unroll
        for (int i = 0; i < 4; ++i) g4[i] = gate[a0 + srow + i * 8];
    }
    for (int kt = 0; kt < K; kt += 64) {
        __syncthreads();
        if (MODE == 2) {
            // A-staging = gated mix of bufA/bufB (reg-staged)
#pragma unroll
            for (int i = 0; i < 4; ++i) {
                size_t ro = (a0 + srow + i * 8) * (size_t)K + kt + scol;
                bf16x8 x = *reinterpret_cast<const bf16x8*>(A + ro);
                bf16x8 y = *reinterpret_cast<const bf16x8*>(A2 + ro);
                bf16x8 o;
#pragma unroll
                for (int j = 0; j < 8; ++j)
                    o[j] = (bf16_t)(g4[i] * (float)x[j] + (1.f - g4[i]) * (float)y[j]);
                *reinterpret_cast<bf16x8*>(&As[srow + i * 8 - (lane >> 3) + (lane >> 3)][scol]) = o;
                // note: srow already includes (lane>>3); row = w*32+i*8+(lane>>3)
            }
        } else {
#pragma unroll
            for (int i = 0; i < 4; ++i)
                gload16(Ap + (a0 + srow + i * 8) * (size_t)K + kt + scol, &As[w * 32 + i * 8][0]);
        }
#pragma unroll
        for (int i = 0; i < 4; ++i)
            gload16(Bp + (b0 + srow + i * 8) * (size_t)K + kt + scol, &Bs[w * 32 + i * 8][0]);
        __syncthreads();
#pragma unroll
        for (int kk = 0; kk < 2; ++kk) {
            bf16x8 af[4], bfr[4];
#pragma unroll
            for (int mi = 0; mi < 4; ++mi)
                af[mi] = *reinterpret_cast<const bf16x8*>(&As[wm * 64 + mi * 16 + l16][kk * 32 + l4 * 8]);
#pragma unroll
            for (int ni = 0; ni < 4; ++ni)
                bfr[ni] = *reinterpret_cast<const bf16x8*>(&Bs[wn * 64 + ni * 16 + l16][kk * 32 + l4 * 8]);
#pragma unroll
            for (int mi = 0; mi < 4; ++mi)
#pragma unroll
                for (int ni = 0; ni < 4; ++ni)
                    acc[mi][ni] = __builtin_amdgcn_mfma_f32_16x16x32_bf16(af[mi], bfr[ni], acc[mi][ni], 0, 0, 0);
        }
    }
    bf16_t* qd = sec ? qdst2 : qdst;
    bf16_t* kd = sec ? kdst2 : kdst;
    bf16_t* vd = sec ? vdst2 : vdst;
#pragma unroll
    for (int mi = 0; mi < 4; ++mi) {
#pragma unroll
        for (int ni = 0; ni < 4; ++ni) {
            int col = (int)b0 + wn * 64 + ni * 16 + l16;
            float bs = bp[col];
            int row0 = (int)a0 + wm * 64 + mi * 16 + l4 * 4;
            float vv[4];
#pragma unroll
            for (int r = 0; r < 4; ++r) vv[r] = acc[mi][ni][r] + bs;
            if (MODE == 0) {
                bf16_t* Cp = (bf16_t*)(sec ? Cout2 : Cout);
#pragma unroll
                for (int r = 0; r < 4; ++r)
                    Cp[(size_t)(row0 + r) * N + col] = (bf16_t)vv[r];
            } else if (MODE == 2) {
#pragma unroll
                for (int r = 0; r < 4; ++r) {
                    size_t idx = (size_t)(row0 + r) * N + col;
                    ((float*)Cout)[idx] = vv[r] + 0.5f * ((float)r1[idx] + (float)r2[idx]);
                }
            } else {
                if (col < 512) {
#pragma unroll
                    for (int r = 0; r < 4; ++r)
                        qd[(size_t)(row0 + r) * 512 + col] = (bf16_t)(vv[r] * 0.090168440f);
                } else if (col < 1024) {
                    int cc = col - 512, h = cc >> 8, d = cc & 255;
#pragma unroll
                    for (int r = 0; r < 4; ++r) {
                        int row = row0 + r;
                        int bh = (row >> 11) * 2 + h, seq = row & 2047;
                        kd[((size_t)(bh * 64 + (seq >> 5))) * 8192 + (d >> 3) * 256 +
                           (seq & 31) * 8 + (d & 7)] = (bf16_t)vv[r];
                    }
                } else {
                    int cc = col - 1024, h = cc >> 8, d = cc & 255;
                    int bh = (row0 >> 11) * 2 + h, seq = row0 & 2047;
                    size_t idx = ((size_t)(bh * 64 + (seq >> 5))) * 8192 +
                                 ((seq >> 3) & 3) * 2048 + d * 8 + (seq & 7);
                    union { bf16_t h4[4]; uint2 u8; } pk;
#pragma unroll
                    for (int r = 0; r < 4; ++r) pk.h4[r] = (bf16_t)vv[r];
                    *reinterpret_cast<uint2*>(&vd[idx]) = pk.u8;
                }
            }
        }
    }
}

// ---------------- gate = sigmoid(sum(rgb_p*event_p, axis=-1)) ----------------
__global__ __launch_bounds__(256) void gate_kernel(const bf16_t* __restrict__ rp,
                                                   const bf16_t* __restrict__ ep,
                                                   float* __restrict__ gate) {
    int row = blockIdx.x * 4 + (threadIdx.x >> 6);
    int lane = threadIdx.x & 63;
    bf16x8 a = reinterpret_cast<const bf16x8*>(rp + (size_t)row * 512)[lane];
    bf16x8 b = reinterpret_cast<const bf16x8*>(ep + (size_t)row * 512)[lane];
    float s = 0.f;
#pragma unroll
    for (int j = 0; j < 8; ++j) s += (float)a[j] * (float)b[j];
#pragma unroll
    for (int off = 32; off; off >>= 1) s += __shfl_xor(s, off, 64);
    if (lane == 0) gate[row] = 1.f / (1.f + __expf(-s));
}

// ---------------- flash attention (R3 phase-serial + exp2 + setprio) --------
// grid 512: bid = qb*32 + dir*16 + bh. 4 waves, wave owns 32 q rows, KVBLK=32.
// K/V double-buffered; one vmcnt(0)+barrier per iter; stage t+1 at body top.
__global__ __launch_bounds__(256, 2) void attn_kernel(const bf16_t* __restrict__ qbr,
                                                      const bf16_t* __restrict__ qbe,
                                                      const bf16_t* __restrict__ kbr,
                                                      const bf16_t* __restrict__ kbe,
                                                      const bf16_t* __restrict__ vbr,
                                                      const bf16_t* __restrict__ vbe,
                                                      bf16_t* __restrict__ out0,
                                                      bf16_t* __restrict__ out1) {
    __shared__ __align__(16) bf16_t smem[32768];  // K[2][8192] | V[2][8192]
    const int bid = blockIdx.x;
    const int qb = bid >> 5;
    const int combo = bid & 31;
    const int dir = combo >> 4;
    const int bh = combo & 15;
    const int b = bh >> 1, h = bh & 1;
    const bf16_t* Qb = dir ? qbe : qbr;
    const bf16_t* Kc = dir ? kbr : kbe;
    const bf16_t* Vc = dir ? vbr : vbe;
    bf16_t* osrc = dir ? out1 : out0;
    const int tid = threadIdx.x;
    const int w = tid >> 6, l = tid & 63;
    const int l31 = l & 31, hi = l >> 5;
    const int q0w = qb * 128 + w * 32;

    const bf16_t* qp = Qb + ((size_t)(b * 2048 + q0w + l31)) * 512 + h * 256 + hi * 8;
    bf16x8 qf[16];
#pragma unroll
    for (int dch = 0; dch < 16; ++dch)
        qf[dch] = *reinterpret_cast<const bf16x8*>(qp + dch * 16);

    f32x16 O[8] = {};
    f32x16 st;
    float mrun = -1e30f, lrun = 0.f;
    union PA { u32 uw[4]; bf16x8 v; } pa0, pa1;

    const bf16_t* kq = Kc + (size_t)bh * 524288 + (w * 2048 + l * 8);
    const bf16_t* vq = Vc + (size_t)bh * 524288 + (w * 2048 + l * 8);

#define STAGE(T, P)                                                    \
    do {                                                               \
        const bf16_t* ks_ = kq + (size_t)(T) * 8192;                   \
        const bf16_t* vs_ = vq + (size_t)(T) * 8192;                   \
        bf16_t* lk_ = &smem[(P) * 8192 + w * 2048];                    \
        bf16_t* lv_ = &smem[16384 + (P) * 8192 + w * 2048];            \
        gload16(ks_, lk_); gload16(ks_ + 512, lk_ + 512);              \
        gload16(ks_ + 1024, lk_ + 1024); gload16(ks_ + 1536, lk_ + 1536); \
        gload16(vs_, lv_); gload16(vs_ + 512, lv_ + 512);              \
        gload16(vs_ + 1024, lv_ + 1024); gload16(vs_ + 1536, lv_ + 1536); \
    } while (0)

    STAGE(0, 0);

    for (int kt2 = 0; kt2 < 64; ++kt2) {
        asm volatile("s_waitcnt vmcnt(0)" ::: "memory");
        __builtin_amdgcn_s_barrier();
        if (kt2 < 63) STAGE(kt2 + 1, (kt2 + 1) & 1);

        const int cb = kt2 & 1;
        const bf16_t* kb = &smem[cb * 8192 + hi * 256 + l31 * 8];
        const bf16_t* vb = &smem[16384 + cb * 8192 + hi * 2048 + l31 * 8];

        // QK^T (swapped): st[r] = S[k=(r&3)+8*(r>>2)+4*hi][q=l31], exp2 domain
#pragma unroll
        for (int r = 0; r < 16; ++r) st[r] = 0.f;
        __builtin_amdgcn_s_setprio(1);
#pragma unroll
        for (int dch = 0; dch < 16; ++dch) {
            bf16x8 kf = *reinterpret_cast<const bf16x8*>(kb + dch * 512);
            st = __builtin_amdgcn_mfma_f32_32x32x16_bf16(kf, qf[dch], st, 0, 0, 0);
        }
        __builtin_amdgcn_s_setprio(0);

        // online softmax (lane-local, q=l31; partner lane ^32 holds other k half)
        float mx = st[0];
#pragma unroll
        for (int r = 1; r < 16; ++r) mx = fmaxf(mx, st[r]);
        mx = fmaxf(mx, __shfl_xor(mx, 32, 64));
        if (__any(mx - mrun > 8.f)) {
            float mnew = fmaxf(mrun, mx);
            float sc = exp2v(mrun - mnew);
            mrun = mnew;
            lrun *= sc;
#pragma unroll
            for (int r = 0; r < 16; ++r) {
                int qr = (r & 3) + 8 * (r >> 2) + 4 * hi;
                float scr = __shfl(sc, qr, 64);
#pragma unroll
                for (int g = 0; g < 8; ++g) O[g][r] *= scr;
            }
        }
        float lsum = 0.f;
        u32 W[8];
#pragma unroll
        for (int m = 0; m < 8; ++m) {
            float plo = exp2v(st[2 * m] - mrun);
            float phi_ = exp2v(st[2 * m + 1] - mrun);
            lsum += plo + phi_;
            W[m] = cvtpk_bf16(plo, phi_);
        }
        lsum += __shfl_xor(lsum, 32, 64);
        lrun += lsum;
        {
            u32 t0 = hi ? W[0] : W[2], t1 = hi ? W[1] : W[3];
            u32 r0 = (u32)__shfl_xor((int)t0, 32, 64);
            u32 r1 = (u32)__shfl_xor((int)t1, 32, 64);
            pa0.uw[0] = hi ? r0 : W[0]; pa0.uw[1] = hi ? r1 : W[1];
            pa0.uw[2] = hi ? W[2] : r0; pa0.uw[3] = hi ? W[3] : r1;
        }
        {
            u32 t0 = hi ? W[4] : W[6], t1 = hi ? W[5] : W[7];
            u32 r0 = (u32)__shfl_xor((int)t0, 32, 64);
            u32 r1 = (u32)__shfl_xor((int)t1, 32, 64);
            pa1.uw[0] = hi ? r0 : W[4]; pa1.uw[1] = hi ? r1 : W[5];
            pa1.uw[2] = hi ? W[6] : r0; pa1.uw[3] = hi ? W[7] : r1;
        }

        // PV
        __builtin_amdgcn_s_setprio(1);
#pragma unroll
        for (int g = 0; g < 8; ++g) {
            bf16x8 v0 = *reinterpret_cast<const bf16x8*>(vb + g * 256);
            O[g] = __builtin_amdgcn_mfma_f32_32x32x16_bf16(pa0.v, v0, O[g], 0, 0, 0);
        }
#pragma unroll
        for (int g = 0; g < 8; ++g) {
            bf16x8 v1 = *reinterpret_cast<const bf16x8*>(vb + 4096 + g * 256);
            O[g] = __builtin_amdgcn_mfma_f32_32x32x16_bf16(pa1.v, v1, O[g], 0, 0, 0);
        }
        __builtin_amdgcn_s_setprio(0);
    }
#undef STAGE

    // normalize (lrun broadcast per q-row) and store
#pragma unroll
    for (int r = 0; r < 16; ++r) {
        int qr = (r & 3) + 8 * (r >> 2) + 4 * hi;
        float linv = 1.0f / __shfl(lrun, qr, 64);
        size_t rowoff = ((size_t)(b * 2048 + q0w + qr)) * 512 + h * 256 + l31;
#pragma unroll
        for (int g = 0; g < 8; ++g)
            osrc[rowoff + g * 32] = (bf16_t)(O[g][r] * linv);
    }
}

extern "C" void kernel_launch(void* const* d_in, const int* in_sizes, int n_in,
                              void* d_out, int out_size, void* d_ws, size_t ws_size,
                              hipStream_t stream) {
    const float* rgb = (const float*)d_in[0];
    const float* event = (const float*)d_in[1];
    const float* w_rgb = (const float*)d_in[2];
    const float* b_rgb = (const float*)d_in[3];
    const float* w_event = (const float*)d_in[4];
    const float* b_event = (const float*)d_in[5];
    const float* w_in = (const float*)d_in[6];
    const float* b_in = (const float*)d_in[7];
    const float* w_out = (const float*)d_in[8];
    const float* b_out = (const float*)d_in[9];
    float* out = (float*)d_out;

    const size_t MB16 = (size_t)16 * 1024 * 1024;
    char* ws = (char*)d_ws;
    bf16_t* wrgb_bf = (bf16_t*)(ws + 0);
    bf16_t* wevt_bf = (bf16_t*)(ws + 524288);
    bf16_t* wout_bf = (bf16_t*)(ws + 1048576);
    bf16_t* win_bf = (bf16_t*)(ws + 1572864);
    float* gate = (float*)(ws + 3145728);
    bf16_t* bufA = (bf16_t*)(ws + 4194304);            // rgb bf16 -> attn out dir0
    bf16_t* bufB = (bf16_t*)(ws + 4194304 + MB16);     // event bf16 -> attn out dir1
    bf16_t* rgbp = (bf16_t*)(ws + 4194304 + 2 * MB16);
    bf16_t* evtp = (bf16_t*)(ws + 4194304 + 3 * MB16);
    bf16_t* qbr  = (bf16_t*)(ws + 4194304 + 4 * MB16);
    bf16_t* qbe  = (bf16_t*)(ws + 4194304 + 5 * MB16);
    bf16_t* kbr  = (bf16_t*)(ws + 4194304 + 6 * MB16);
    bf16_t* kbe  = (bf16_t*)(ws + 4194304 + 7 * MB16);
    bf16_t* vbr  = (bf16_t*)(ws + 4194304 + 8 * MB16);
    bf16_t* vbe  = (bf16_t*)(ws + 4194304 + 9 * MB16);

    dim3 blk(256);
    // all converts in one dispatch
    f2b_all<<<8960, blk, 0, stream>>>(rgb, bufA, event, bufB, w_rgb, wrgb_bf,
                                      w_event, wevt_bf, w_in, win_bf, w_out, wout_bf);
    // input projections (merged): y<128 -> rgb, y>=128 -> event
    gemm_bt<0><<<dim3(4, 256), blk, 0, stream>>>(bufA, bufB, wrgb_bf, wevt_bf, b_rgb, b_event,
                                                 rgbp, evtp, nullptr, nullptr, nullptr,
                                                 nullptr, nullptr, nullptr, nullptr, nullptr,
                                                 nullptr, 512, 512);
    // gate
    gate_kernel<<<4096, blk, 0, stream>>>(rgbp, evtp, gate);
    // QKV projections (merged) -> Q compact + K/V chunked layouts
    gemm_bt<1><<<dim3(12, 256), blk, 0, stream>>>(rgbp, evtp, win_bf, win_bf, b_in, b_in,
                                                  nullptr, nullptr, nullptr, nullptr, nullptr,
                                                  qbr, kbr, vbr, qbe, kbe, vbe, 1536, 512);
    // attention both directions
    attn_kernel<<<512, blk, 0, stream>>>(qbr, qbe, kbr, kbe, vbr, vbe, bufA, bufB);
    // final projection: A-staging = gate-mix(bufA,bufB); f32 out + residual
    gemm_bt<2><<<dim3(4, 128), blk, 0, stream>>>(bufA, bufB, wout_bf, nullptr, b_out, nullptr,
                                                 out, nullptr, rgbp, evtp, gate,
                                                 nullptr, nullptr, nullptr, nullptr, nullptr,
                                                 nullptr, 512, 512);
}